// Round 6
// baseline (637.582 us; speedup 1.0000x reference)
//
#include <hip/hip_runtime.h>
#include <cstdint>

#define IN_F  1024
#define OUT_F 1024
#define NORD  13
#define BROWS 8192   // 4*2048

typedef __bf16 bf16x8 __attribute__((ext_vector_type(8)));
typedef float  f32x4  __attribute__((ext_vector_type(4)));
typedef unsigned short u16x8 __attribute__((ext_vector_type(8)));
typedef unsigned short u16x4 __attribute__((ext_vector_type(4)));

__device__ __forceinline__ unsigned short f2bf(float f) {
  unsigned int u = __float_as_uint(f);
  unsigned int r = u + 0x7FFFu + ((u >> 16) & 1u);
  return (unsigned short)(r >> 16);
}
__device__ __forceinline__ float bf2f(unsigned short h) {
  return __uint_as_float(((unsigned int)h) << 16);
}
__device__ __forceinline__ float bfround(float f) { return bf2f(f2bf(f)); }

// global -> LDS async copy, 16B per lane.
__device__ __forceinline__ void gload_lds16(const void* g, void* l) {
  __builtin_amdgcn_global_load_lds(
      (__attribute__((address_space(1))) unsigned int*)(uintptr_t)g,
      (__attribute__((address_space(3))) unsigned int*)(unsigned int)(uintptr_t)l,
      16, 0, 0);
}

// ---------------- activation matrix: A[row][bb*1024+f] (bf16) ----------------
__global__ __launch_bounds__(256)
void act_kernel(const float* __restrict__ x, unsigned short* __restrict__ A,
                int b0, int nb, int Kp) {
  int t   = threadIdx.x;
  int row = blockIdx.x * 2 + (t >> 7);
  int f0  = (t & 127) * 8;
  const float* xr = x + (size_t)row * IN_F + f0;
  float xv[8];
  *(float4*)&xv[0] = *(const float4*)&xr[0];
  *(float4*)&xv[4] = *(const float4*)&xr[4];
  unsigned short* Ar = A + (size_t)row * Kp;
  int omax = b0 + nb - 1;
  if (b0 == 0) {
    // JAX bf16 silu: sigmoid rounded to bf16, then x*sigmoid rounded to bf16
    u16x8 sv;
#pragma unroll
    for (int i = 0; i < 8; i++) {
      float xc = bfround(xv[i]);
      float sg = bfround(1.0f / (1.0f + expf(-xc)));
      sv[i] = f2bf(xc * sg);
    }
    *(u16x8*)&Ar[f0] = sv;
  }
  float xs[8], tp[8], tc[8];
#pragma unroll
  for (int i = 0; i < 8; i++) { xs[i] = tanhf(xv[i]); tp[i] = 1.0f; tc[i] = xs[i]; }
  for (int o = 1; o <= omax; o++) {
    if (o >= b0) {
      int bb = o - b0;
      u16x8 sv;
#pragma unroll
      for (int i = 0; i < 8; i++) sv[i] = f2bf(tc[i]);
      *(u16x8*)&Ar[(size_t)bb * 1024 + f0] = sv;
    }
    {
#pragma clang fp contract(off)
#pragma unroll
      for (int i = 0; i < 8; i++) {
        float tm = 2.0f * xs[i] * tc[i];
        float tn = tm - tp[i];
        tp[i] = tc[i]; tc[i] = tn;
      }
    }
  }
}

// ---------------- weight transpose (vectorized): Wt[n][bb*1024+f] = bf16(src_b[f][n]) ----
__global__ __launch_bounds__(256)
void wprep_kernel(const float* __restrict__ baseW, const float* __restrict__ poly,
                  unsigned short* __restrict__ Wt, int b0, int Kp) {
  __shared__ float tile[64][65];
  int bb = blockIdx.z;
  int g  = b0 + bb;
  const float* src = (g == 0) ? baseW : (poly + (size_t)g * (IN_F * OUT_F));
  int n0 = blockIdx.x * 64, f0 = blockIdx.y * 64;
  int t  = threadIdx.x;
  int fl = t >> 4, n4 = (t & 15) * 4;   // load: float4 per thread, coalesced rows
#pragma unroll
  for (int i = 0; i < 4; i++) {
    int f = fl + 16 * i;
    float4 v = *(const float4*)&src[(size_t)(f0 + f) * OUT_F + n0 + n4];
    tile[f][n4 + 0] = v.x; tile[f][n4 + 1] = v.y;
    tile[f][n4 + 2] = v.z; tile[f][n4 + 3] = v.w;
  }
  __syncthreads();
  int f8 = (t & 7) * 8, nl = t >> 3;    // store: u16x8 per thread (2-way bank = free)
#pragma unroll
  for (int i = 0; i < 2; i++) {
    int n = nl + 32 * i;
    u16x8 o;
#pragma unroll
    for (int j = 0; j < 8; j++) o[j] = f2bf(tile[f8 + j][n]);
    *(u16x8*)&Wt[(size_t)(n0 + n) * Kp + (size_t)bb * 1024 + f0 + f8] = o;
  }
}

// ---------------- bias = colsum of bf16(pw0), two-phase parallel ----------------
__global__ __launch_bounds__(256)
void bias1_kernel(const float* __restrict__ pw0, float* __restrict__ partial) {
  int t  = threadIdx.x;
  int n  = blockIdx.x * 256 + t;
  int fc = blockIdx.y;            // 8 f-chunks of 128
  float s = 0.f;
  for (int f = fc * 128; f < fc * 128 + 128; f++)
    s += bf2f(f2bf(pw0[(size_t)f * OUT_F + n]));
  partial[(size_t)fc * OUT_F + n] = s;
}
__global__ __launch_bounds__(256)
void bias2_kernel(const float* __restrict__ partial, float* __restrict__ bias) {
  int n = blockIdx.x * 256 + threadIdx.x;
  float s = 0.f;
#pragma unroll
  for (int fc = 0; fc < 8; fc++) s += partial[(size_t)fc * OUT_F + n];
  bias[n] = s;
}

// ---------------- GEMM: A streamed global->VGPR, B staged in dbuf LDS ----------------
// 128x128 tile, BK=64. A-fragments loaded directly from row-major A (lane pattern
// matches MFMA A-layout), ping-pong prefetched one kt ahead. Only B goes through LDS
// (halves LDS read BW - the binding pipe). Grid (64 m, 8 n): id%8==m%8 -> XCD locality.
__global__ __launch_bounds__(256, 2)
void gemm_kernel(const unsigned short* __restrict__ A, const unsigned short* __restrict__ Wt,
                 unsigned short* __restrict__ outAcc, const float* __restrict__ bias,
                 int Kp, int isFirst) {
  __shared__ unsigned short sB[2][128 * 64];  // 2 x 16 KB
  int t    = threadIdx.x;
  int m0   = blockIdx.x * 128;
  int n0   = blockIdx.y * 128;
  int wave = t >> 6, lane = t & 63;
  int lr   = lane & 15, quad = lane >> 4;
  int wm   = (wave & 1) * 64, wn = (wave >> 1) * 64;

  // B staging: thread t -> row rs (32-row rounds), XOR-swizzled 16B slots
  int rs = t >> 3;
  int jg = (t & 7) ^ (rs & 7);
  const unsigned short* bSrc = Wt + (size_t)(n0 + rs) * Kp + jg * 8;
  char* sBc = (char*)sB;
  int ldsOff = t * 16;

  // A fragment global row bases (+ quad k-offset)
  size_t aRow[4];
#pragma unroll
  for (int mi = 0; mi < 4; mi++)
    aRow[mi] = (size_t)(m0 + wm + mi * 16 + lr) * Kp + quad * 8;

  int bOff[4][2];
#pragma unroll
  for (int ni = 0; ni < 4; ni++) {
    int row = wn + ni * 16 + lr;
#pragma unroll
    for (int ks = 0; ks < 2; ks++) {
      int j = ks * 4 + quad;
      bOff[ni][ks] = row * 128 + ((j ^ (row & 7)) * 16);
    }
  }

  // running bf16-valued sum s
  f32x4 s[4][4];
  float bsr[4];
  if (isFirst) {
#pragma unroll
    for (int ni = 0; ni < 4; ni++) bsr[ni] = bfround(bias[n0 + wn + ni * 16 + lr]);
  } else {
#pragma unroll
    for (int ni = 0; ni < 4; ni++) {
      int gn = n0 + wn + ni * 16 + lr;
#pragma unroll
      for (int mi = 0; mi < 4; mi++) {
        int gmBase = m0 + wm + mi * 16 + quad * 4;
#pragma unroll
        for (int r = 0; r < 4; r++)
          s[mi][ni][r] = bf2f(outAcc[(size_t)(gmBase + r) * OUT_F + gn]);
      }
    }
  }

  int nKt  = Kp >> 6;    // 64-K steps
  int nBlk = Kp >> 10;   // 1024-K order blocks

  auto stageB = [&](int gkt, int buf) {
    const unsigned short* bP = bSrc + gkt * 64;
    char* dB = sBc + buf * 16384 + ldsOff;
#pragma unroll
    for (int rd = 0; rd < 4; rd++)
      gload_lds16(bP + (size_t)rd * 32 * Kp, dB + rd * 4096);
  };

  bf16x8 aEv[4][2], aOd[4][2];
  auto loadA = [&](int gkt, bf16x8 (&dst)[4][2]) {
#pragma unroll
    for (int mi = 0; mi < 4; mi++)
#pragma unroll
      for (int ks = 0; ks < 2; ks++)
        dst[mi][ks] = *(const bf16x8*)(A + aRow[mi] + gkt * 64 + ks * 32);
  };

  stageB(0, 0);     // prologue
  loadA(0, aEv);

  int gkt = 0;
  for (int blk = 0; blk < nBlk; blk++) {
    f32x4 acc[4][4];
#pragma unroll
    for (int mi = 0; mi < 4; mi++)
#pragma unroll
      for (int ni = 0; ni < 4; ni++)
        acc[mi][ni] = (f32x4){0.f, 0.f, 0.f, 0.f};

    auto step = [&](bf16x8 (&cur)[4][2], bf16x8 (&nxt)[4][2]) {
      __syncthreads();                 // drains DMA for tile gkt, frees buf^1
      int buf = gkt & 1;
      int nn  = gkt + 1;
      if (nn < nKt) { stageB(nn, buf ^ 1); loadA(nn, nxt); }
      char* bB = sBc + buf * 16384;
#pragma unroll
      for (int ks = 0; ks < 2; ks++) {
        bf16x8 bfr[4];
#pragma unroll
        for (int ni = 0; ni < 4; ni++) bfr[ni] = *(const bf16x8*)(bB + bOff[ni][ks]);
#pragma unroll
        for (int mi = 0; mi < 4; mi++)
#pragma unroll
          for (int ni = 0; ni < 4; ni++)
            acc[mi][ni] = __builtin_amdgcn_mfma_f32_16x16x32_bf16(cur[mi][ks], bfr[ni], acc[mi][ni], 0, 0, 0);
      }
      gkt++;
    };

    for (int kt2 = 0; kt2 < 8; kt2++) {   // 16 kt per order block, explicit ping-pong
      step(aEv, aOd);
      step(aOd, aEv);
    }

    // bf16 chain update at the order-block boundary (matches ref rounding)
    bool firstBlk = (isFirst && blk == 0);
    if (firstBlk) {
#pragma unroll
      for (int mi = 0; mi < 4; mi++)
#pragma unroll
        for (int ni = 0; ni < 4; ni++)
#pragma unroll
          for (int r = 0; r < 4; r++) {
            float p = bfround(acc[mi][ni][r]);          // out = bf16 matmul result
            s[mi][ni][r] = bfround(p + bsr[ni]);        // out = bf16(out + bf16(bias))
          }
    } else {
#pragma unroll
      for (int mi = 0; mi < 4; mi++)
#pragma unroll
        for (int ni = 0; ni < 4; ni++)
#pragma unroll
          for (int r = 0; r < 4; r++)
            s[mi][ni][r] = bfround(s[mi][ni][r] + bfround(acc[mi][ni][r]));
    }
  }

  // store running sum as bf16 (values are exactly bf16-representable)
#pragma unroll
  for (int ni = 0; ni < 4; ni++) {
    int gn = n0 + wn + ni * 16 + lr;
#pragma unroll
    for (int mi = 0; mi < 4; mi++) {
      int gmBase = m0 + wm + mi * 16 + quad * 4;
#pragma unroll
      for (int r = 0; r < 4; r++)
        outAcc[(size_t)(gmBase + r) * OUT_F + gn] = f2bf(s[mi][ni][r]);
    }
  }
}

// ---------------- RMSNorm on bf16 outAcc ----------------
__global__ __launch_bounds__(256)
void rms_kernel(const unsigned short* __restrict__ outAcc, const float* __restrict__ scale,
                float* __restrict__ out) {
  int row = blockIdx.x;
  int t   = threadIdx.x;
  const unsigned short* src = outAcc + (size_t)row * OUT_F;
  u16x4 hv = *(const u16x4*)&src[t * 4];
  float v[4];
#pragma unroll
  for (int i = 0; i < 4; i++) v[i] = bf2f(hv[i]);
  float s = v[0]*v[0] + v[1]*v[1] + v[2]*v[2] + v[3]*v[3];
#pragma unroll
  for (int off = 32; off > 0; off >>= 1) s += __shfl_down(s, off, 64);
  __shared__ float red[4];
  if ((t & 63) == 0) red[t >> 6] = s;
  __syncthreads();
  float tot = red[0] + red[1] + red[2] + red[3];
  float sc = 1.0f / sqrtf(tot * (1.0f / OUT_F) + 1e-6f);
  float4 so = *(const float4*)&scale[t * 4];
  float4 o;
  o.x = v[0] * sc * so.x; o.y = v[1] * sc * so.y;
  o.z = v[2] * sc * so.z; o.w = v[3] * sc * so.w;
  *(float4*)&out[(size_t)row * OUT_F + t * 4] = o;
}

extern "C" void kernel_launch(void* const* d_in, const int* in_sizes, int n_in,
                              void* d_out, int out_size, void* d_ws, size_t ws_size,
                              hipStream_t stream) {
  const float* x     = (const float*)d_in[0];
  const float* baseW = (const float*)d_in[1];
  const float* poly  = (const float*)d_in[2];
  const float* scale = (const float*)d_in[3];
  float* out = (float*)d_out;

  char* ws = (char*)d_ws;
  unsigned short* outAcc = (unsigned short*)ws;        // 8192*1024*2 = 16777216 B
  float* bias    = (float*)(ws + 16777216);            // 4096 B
  float* partial = (float*)(ws + 16777216 + 4096);     // 8*1024*4 = 32768 B
  size_t fixed   = 16777216 + 4096 + 32768;

  int CHB = 1;
  for (int c = NORD; c >= 1; c--) {
    size_t need = fixed + (size_t)c * 1024 * OUT_F * 2
                + (size_t)BROWS * c * 1024 * 2;
    if (need <= ws_size) { CHB = c; break; }
  }
  unsigned short* Wt = (unsigned short*)(ws + fixed);
  unsigned short* Ap = (unsigned short*)(ws + fixed + (size_t)CHB * 1024 * OUT_F * 2);

  bias1_kernel<<<dim3(4, 8), 256, 0, stream>>>(poly, partial);
  bias2_kernel<<<4, 256, 0, stream>>>(partial, bias);

  for (int b0 = 0; b0 < NORD; b0 += CHB) {
    int nb = (CHB < NORD - b0) ? CHB : (NORD - b0);
    int Kp = nb * 1024;
    act_kernel<<<BROWS / 2, 256, 0, stream>>>(x, Ap, b0, nb, Kp);
    wprep_kernel<<<dim3(16, 16, nb), 256, 0, stream>>>(baseW, poly, Wt, b0, Kp);
    gemm_kernel<<<dim3(BROWS / 128, 8), 256, 0, stream>>>(Ap, Wt, outAcc, bias, Kp, (b0 == 0) ? 1 : 0);
  }
  rms_kernel<<<BROWS, 256, 0, stream>>>(outAcc, scale, out);
}

// Round 7
// 465.198 us; speedup vs baseline: 1.3706x; 1.3706x over previous
//
#include <hip/hip_runtime.h>
#include <cstdint>

#define IN_F  1024
#define OUT_F 1024
#define NORD  13
#define BROWS 8192   // 4*2048

typedef __bf16 bf16x8 __attribute__((ext_vector_type(8)));
typedef float  f32x4  __attribute__((ext_vector_type(4)));
typedef unsigned short u16x8 __attribute__((ext_vector_type(8)));
typedef unsigned short u16x4 __attribute__((ext_vector_type(4)));

__device__ __forceinline__ unsigned short f2bf(float f) {
  unsigned int u = __float_as_uint(f);
  unsigned int r = u + 0x7FFFu + ((u >> 16) & 1u);
  return (unsigned short)(r >> 16);
}
__device__ __forceinline__ float bf2f(unsigned short h) {
  return __uint_as_float(((unsigned int)h) << 16);
}
__device__ __forceinline__ float bfround(float f) { return bf2f(f2bf(f)); }

// global -> LDS async copy, 16B per lane.
__device__ __forceinline__ void gload_lds16(const void* g, void* l) {
  __builtin_amdgcn_global_load_lds(
      (__attribute__((address_space(1))) unsigned int*)(uintptr_t)g,
      (__attribute__((address_space(3))) unsigned int*)(unsigned int)(uintptr_t)l,
      16, 0, 0);
}

// ---------------- activation matrix: A[row][bb*1024+f] (bf16) ----------------
__global__ __launch_bounds__(256)
void act_kernel(const float* __restrict__ x, unsigned short* __restrict__ A,
                int b0, int nb, int Kp) {
  int t   = threadIdx.x;
  int row = blockIdx.x * 2 + (t >> 7);
  int f0  = (t & 127) * 8;
  const float* xr = x + (size_t)row * IN_F + f0;
  float xv[8];
  *(float4*)&xv[0] = *(const float4*)&xr[0];
  *(float4*)&xv[4] = *(const float4*)&xr[4];
  unsigned short* Ar = A + (size_t)row * Kp;
  int omax = b0 + nb - 1;
  if (b0 == 0) {
    // JAX bf16 silu: sigmoid rounded to bf16, then x*sigmoid rounded to bf16
    u16x8 sv;
#pragma unroll
    for (int i = 0; i < 8; i++) {
      float xc = bfround(xv[i]);
      float sg = bfround(1.0f / (1.0f + expf(-xc)));
      sv[i] = f2bf(xc * sg);
    }
    *(u16x8*)&Ar[f0] = sv;
  }
  float xs[8], tp[8], tc[8];
#pragma unroll
  for (int i = 0; i < 8; i++) { xs[i] = tanhf(xv[i]); tp[i] = 1.0f; tc[i] = xs[i]; }
  for (int o = 1; o <= omax; o++) {
    if (o >= b0) {
      int bb = o - b0;
      u16x8 sv;
#pragma unroll
      for (int i = 0; i < 8; i++) sv[i] = f2bf(tc[i]);
      *(u16x8*)&Ar[(size_t)bb * 1024 + f0] = sv;
    }
    {
#pragma clang fp contract(off)
#pragma unroll
      for (int i = 0; i < 8; i++) {
        float tm = 2.0f * xs[i] * tc[i];
        float tn = tm - tp[i];
        tp[i] = tc[i]; tc[i] = tn;
      }
    }
  }
}

// ---------------- weight transpose (vectorized): Wt[n][bb*1024+f] = bf16(src_b[f][n]) ----
__global__ __launch_bounds__(256)
void wprep_kernel(const float* __restrict__ baseW, const float* __restrict__ poly,
                  unsigned short* __restrict__ Wt, int b0, int Kp) {
  __shared__ float tile[64][65];
  int bb = blockIdx.z;
  int g  = b0 + bb;
  const float* src = (g == 0) ? baseW : (poly + (size_t)g * (IN_F * OUT_F));
  int n0 = blockIdx.x * 64, f0 = blockIdx.y * 64;
  int t  = threadIdx.x;
  int fl = t >> 4, n4 = (t & 15) * 4;   // load: float4 per thread, coalesced rows
#pragma unroll
  for (int i = 0; i < 4; i++) {
    int f = fl + 16 * i;
    float4 v = *(const float4*)&src[(size_t)(f0 + f) * OUT_F + n0 + n4];
    tile[f][n4 + 0] = v.x; tile[f][n4 + 1] = v.y;
    tile[f][n4 + 2] = v.z; tile[f][n4 + 3] = v.w;
  }
  __syncthreads();
  int f8 = (t & 7) * 8, nl = t >> 3;    // store: u16x8 per thread
#pragma unroll
  for (int i = 0; i < 2; i++) {
    int n = nl + 32 * i;
    u16x8 o;
#pragma unroll
    for (int j = 0; j < 8; j++) o[j] = f2bf(tile[f8 + j][n]);
    *(u16x8*)&Wt[(size_t)(n0 + n) * Kp + (size_t)bb * 1024 + f0 + f8] = o;
  }
}

// ---------------- bias partials: partial[fc][n] = sum_{f in chunk} bf16(pw0[f][n]) ----
__global__ __launch_bounds__(256)
void bias1_kernel(const float* __restrict__ pw0, float* __restrict__ partial) {
  int t  = threadIdx.x;
  int n  = blockIdx.x * 256 + t;
  int fc = blockIdx.y;            // 8 f-chunks of 128
  float s = 0.f;
  for (int f = fc * 128; f < fc * 128 + 128; f++)
    s += bf2f(f2bf(pw0[(size_t)f * OUT_F + n]));
  partial[(size_t)fc * OUT_F + n] = s;
}

// ---------------- GEMM: BK=32, dbuf LDS (32 KB/block -> 3 blocks/CU), 1 barrier/kt ----
// 128x128 tile. Grid (64 m, 8 n): id%8==m%8 -> XCD locality. Running bf16 chain packed
// into u32 pairs to fit the 3-waves/EU register budget. XOR swizzle in 16B units (4 slots).
__global__ __launch_bounds__(256, 3)
void gemm_kernel(const unsigned short* __restrict__ A, const unsigned short* __restrict__ Wt,
                 unsigned short* __restrict__ outAcc, const float* __restrict__ partial,
                 int Kp, int isFirst) {
  __shared__ unsigned short sA[2][128 * 32];  // 2 x 8 KB
  __shared__ unsigned short sB[2][128 * 32];  // 2 x 8 KB
  int t    = threadIdx.x;
  int m0   = blockIdx.x * 128;
  int n0   = blockIdx.y * 128;
  int wave = t >> 6, lane = t & 63;
  int lr   = lane & 15, quad = lane >> 4;
  int wm   = (wave & 1) * 64, wn = (wave >> 1) * 64;

  // staging: row rs = t>>2 (2 rounds of 64 rows), phys slot t&3, logical k-block jg
  int rs = t >> 2;
  int jg = (t & 3) ^ (rs & 3);
  const unsigned short* aSrc = A  + (size_t)(m0 + rs) * Kp + jg * 8;
  const unsigned short* bSrc = Wt + (size_t)(n0 + rs) * Kp + jg * 8;
  char* sAc = (char*)sA;
  char* sBc = (char*)sB;
  int ldsOff = t * 16;

  // fragment LDS byte offsets (row stride 64 B, slot = quad ^ (row&3))
  int aOff[4], bOff[4];
#pragma unroll
  for (int mi = 0; mi < 4; mi++) {
    int row = wm + mi * 16 + lr;
    aOff[mi] = row * 64 + ((quad ^ (row & 3)) * 16);
  }
#pragma unroll
  for (int ni = 0; ni < 4; ni++) {
    int row = wn + ni * 16 + lr;
    bOff[ni] = row * 64 + ((quad ^ (row & 3)) * 16);
  }

  // running bf16 chain, packed: sp[mi][ni][p] = bf16(s[2p]) | bf16(s[2p+1])<<16
  unsigned int sp[4][4][2];
  float bsr[4];
  if (isFirst) {
#pragma unroll
    for (int ni = 0; ni < 4; ni++) {
      int gn = n0 + wn + ni * 16 + lr;
      float bsum = 0.f;
#pragma unroll
      for (int fc = 0; fc < 8; fc++) bsum += partial[(size_t)fc * OUT_F + gn];
      bsr[ni] = bfround(bsum);
    }
  } else {
#pragma unroll
    for (int ni = 0; ni < 4; ni++) {
      int gn = n0 + wn + ni * 16 + lr;
#pragma unroll
      for (int mi = 0; mi < 4; mi++) {
        int gmBase = m0 + wm + mi * 16 + quad * 4;
#pragma unroll
        for (int p = 0; p < 2; p++) {
          unsigned int lo = outAcc[(size_t)(gmBase + 2 * p) * OUT_F + gn];
          unsigned int hi = outAcc[(size_t)(gmBase + 2 * p + 1) * OUT_F + gn];
          sp[mi][ni][p] = lo | (hi << 16);
        }
      }
    }
  }

  int nKt = Kp >> 5;     // 32-K steps

  auto stage = [&](int gkt, int buf) {
    const unsigned short* aP = aSrc + gkt * 32;
    const unsigned short* bP = bSrc + gkt * 32;
    char* dA = sAc + buf * 8192 + ldsOff;
    char* dB = sBc + buf * 8192 + ldsOff;
#pragma unroll
    for (int rd = 0; rd < 2; rd++)
      gload_lds16(aP + (size_t)rd * 64 * Kp, dA + rd * 4096);
#pragma unroll
    for (int rd = 0; rd < 2; rd++)
      gload_lds16(bP + (size_t)rd * 64 * Kp, dB + rd * 4096);
  };

  stage(0, 0);  // prologue

  int gkt = 0;
  int nBlk = Kp >> 10;
  for (int blk = 0; blk < nBlk; blk++) {
    f32x4 acc[4][4];
#pragma unroll
    for (int mi = 0; mi < 4; mi++)
#pragma unroll
      for (int ni = 0; ni < 4; ni++)
        acc[mi][ni] = (f32x4){0.f, 0.f, 0.f, 0.f};

    for (int kt = 0; kt < 32; kt++, gkt++) {
      __syncthreads();               // drains DMA for tile gkt (issued 1 iter ago)
      int nxt = gkt + 1;
      if (nxt < nKt) stage(nxt, nxt & 1);
      int buf = gkt & 1;
      char* bA = sAc + buf * 8192;
      char* bB = sBc + buf * 8192;
      bf16x8 af[4], bfr[4];
#pragma unroll
      for (int mi = 0; mi < 4; mi++) af[mi] = *(const bf16x8*)(bA + aOff[mi]);
#pragma unroll
      for (int ni = 0; ni < 4; ni++) bfr[ni] = *(const bf16x8*)(bB + bOff[ni]);
#pragma unroll
      for (int mi = 0; mi < 4; mi++)
#pragma unroll
        for (int ni = 0; ni < 4; ni++)
          acc[mi][ni] = __builtin_amdgcn_mfma_f32_16x16x32_bf16(af[mi], bfr[ni], acc[mi][ni], 0, 0, 0);
    }

    // bf16 chain update at the order-block boundary (matches ref rounding)
    bool firstBlk = (isFirst && blk == 0);
#pragma unroll
    for (int mi = 0; mi < 4; mi++)
#pragma unroll
      for (int ni = 0; ni < 4; ni++)
#pragma unroll
        for (int p = 0; p < 2; p++) {
          float a0 = bfround(acc[mi][ni][2 * p]);
          float a1 = bfround(acc[mi][ni][2 * p + 1]);
          float s0, s1;
          if (firstBlk) {
            s0 = bfround(a0 + bsr[ni]);
            s1 = bfround(a1 + bsr[ni]);
          } else {
            unsigned int w = sp[mi][ni][p];
            s0 = bfround(bf2f((unsigned short)(w & 0xffff)) + a0);
            s1 = bfround(bf2f((unsigned short)(w >> 16)) + a1);
          }
          sp[mi][ni][p] = (unsigned int)f2bf(s0) | ((unsigned int)f2bf(s1) << 16);
        }
  }

  // store running sum (already bf16 bit patterns)
#pragma unroll
  for (int ni = 0; ni < 4; ni++) {
    int gn = n0 + wn + ni * 16 + lr;
#pragma unroll
    for (int mi = 0; mi < 4; mi++) {
      int gmBase = m0 + wm + mi * 16 + quad * 4;
#pragma unroll
      for (int p = 0; p < 2; p++) {
        unsigned int w = sp[mi][ni][p];
        outAcc[(size_t)(gmBase + 2 * p) * OUT_F + gn]     = (unsigned short)(w & 0xffff);
        outAcc[(size_t)(gmBase + 2 * p + 1) * OUT_F + gn] = (unsigned short)(w >> 16);
      }
    }
  }
}

// ---------------- RMSNorm on bf16 outAcc ----------------
__global__ __launch_bounds__(256)
void rms_kernel(const unsigned short* __restrict__ outAcc, const float* __restrict__ scale,
                float* __restrict__ out) {
  int row = blockIdx.x;
  int t   = threadIdx.x;
  const unsigned short* src = outAcc + (size_t)row * OUT_F;
  u16x4 hv = *(const u16x4*)&src[t * 4];
  float v[4];
#pragma unroll
  for (int i = 0; i < 4; i++) v[i] = bf2f(hv[i]);
  float s = v[0]*v[0] + v[1]*v[1] + v[2]*v[2] + v[3]*v[3];
#pragma unroll
  for (int off = 32; off > 0; off >>= 1) s += __shfl_down(s, off, 64);
  __shared__ float red[4];
  if ((t & 63) == 0) red[t >> 6] = s;
  __syncthreads();
  float tot = red[0] + red[1] + red[2] + red[3];
  float sc = 1.0f / sqrtf(tot * (1.0f / OUT_F) + 1e-6f);
  float4 so = *(const float4*)&scale[t * 4];
  float4 o;
  o.x = v[0] * sc * so.x; o.y = v[1] * sc * so.y;
  o.z = v[2] * sc * so.z; o.w = v[3] * sc * so.w;
  *(float4*)&out[(size_t)row * OUT_F + t * 4] = o;
}

extern "C" void kernel_launch(void* const* d_in, const int* in_sizes, int n_in,
                              void* d_out, int out_size, void* d_ws, size_t ws_size,
                              hipStream_t stream) {
  const float* x     = (const float*)d_in[0];
  const float* baseW = (const float*)d_in[1];
  const float* poly  = (const float*)d_in[2];
  const float* scale = (const float*)d_in[3];
  float* out = (float*)d_out;

  char* ws = (char*)d_ws;
  unsigned short* outAcc = (unsigned short*)ws;        // 8192*1024*2 = 16777216 B
  float* partial = (float*)(ws + 16777216);            // 8*1024*4 = 32768 B
  size_t fixed   = 16777216 + 32768;

  int CHB = 1;
  for (int c = NORD; c >= 1; c--) {
    size_t need = fixed + (size_t)c * 1024 * OUT_F * 2
                + (size_t)BROWS * c * 1024 * 2;
    if (need <= ws_size) { CHB = c; break; }
  }
  unsigned short* Wt = (unsigned short*)(ws + fixed);
  unsigned short* Ap = (unsigned short*)(ws + fixed + (size_t)CHB * 1024 * OUT_F * 2);

  bias1_kernel<<<dim3(4, 8), 256, 0, stream>>>(poly, partial);

  for (int b0 = 0; b0 < NORD; b0 += CHB) {
    int nb = (CHB < NORD - b0) ? CHB : (NORD - b0);
    int Kp = nb * 1024;
    act_kernel<<<BROWS / 2, 256, 0, stream>>>(x, Ap, b0, nb, Kp);
    wprep_kernel<<<dim3(16, 16, nb), 256, 0, stream>>>(baseW, poly, Wt, b0, Kp);
    gemm_kernel<<<dim3(BROWS / 128, 8), 256, 0, stream>>>(Ap, Wt, outAcc, partial, Kp, (b0 == 0) ? 1 : 0);
  }
  rms_kernel<<<BROWS, 256, 0, stream>>>(outAcc, scale, out);
}